// Round 1
// baseline (154.133 us; speedup 1.0000x reference)
//
#include <hip/hip_runtime.h>

// out[bc, 2d+k0, 2y+k1, 2z+k2] = x[bc,d,y,z] * p[k0*4+k1*2+k2] + m[...]
// x: (64, 64, 64, 64) fp32 flat (bc = b*c = 64), out: (64, 128, 128, 128) fp32.
// Each thread: 1 float4 load (4 z-voxels), 8 float4 stores (4 (k0,k1) rows x 2).
__global__ __launch_bounds__(256) void upsample_pca3d_kernel(
    const float* __restrict__ x,
    const float* __restrict__ mean,
    const float* __restrict__ pca,     // (8,1) flat
    float* __restrict__ out,
    int n4)                            // N/4 = 4194304
{
    float p[8], m[8];
#pragma unroll
    for (int k = 0; k < 8; ++k) { p[k] = pca[k]; m[k] = mean[k]; }

    const float4* __restrict__ x4 = reinterpret_cast<const float4*>(x);

    const int stride = gridDim.x * blockDim.x;
    for (int i = blockIdx.x * blockDim.x + threadIdx.x; i < n4; i += stride) {
        float4 v = x4[i];

        // i = ((bc*64 + d)*64 + y)*16 + zq   (zq = z/4)
        int zq = i & 15;
        int y  = (i >> 4) & 63;
        int d  = (i >> 10) & 63;
        int bc = i >> 16;

        // out base: ((bc*128 + 2d)*128 + 2y)*128 + 8*zq   (max ~134M, fits int)
        int base = (((bc << 7) + (d << 1)) << 7) + (y << 1);
        base = (base << 7) + (zq << 3);

        float vv[4] = {v.x, v.y, v.z, v.w};

#pragma unroll
        for (int k0 = 0; k0 < 2; ++k0) {
#pragma unroll
            for (int k1 = 0; k1 < 2; ++k1) {
                const int kA = k0 * 4 + k1 * 2;
                const float pA = p[kA],     pB = p[kA + 1];
                const float mA = m[kA],     mB = m[kA + 1];
                int rowbase = base + k0 * (128 * 128) + k1 * 128;

                float4 o0 = make_float4(fmaf(vv[0], pA, mA), fmaf(vv[0], pB, mB),
                                        fmaf(vv[1], pA, mA), fmaf(vv[1], pB, mB));
                float4 o1 = make_float4(fmaf(vv[2], pA, mA), fmaf(vv[2], pB, mB),
                                        fmaf(vv[3], pA, mA), fmaf(vv[3], pB, mB));
                *reinterpret_cast<float4*>(out + rowbase)     = o0;
                *reinterpret_cast<float4*>(out + rowbase + 4) = o1;
            }
        }
    }
}

extern "C" void kernel_launch(void* const* d_in, const int* in_sizes, int n_in,
                              void* d_out, int out_size, void* d_ws, size_t ws_size,
                              hipStream_t stream) {
    const float* x    = (const float*)d_in[0];
    const float* mean = (const float*)d_in[1];
    const float* pca  = (const float*)d_in[2];
    // d_in[3] (output_shape) unused — shapes are compile-time constants here.
    float* out = (float*)d_out;

    const int n4 = in_sizes[0] / 4;          // 16777216 / 4 = 4194304
    const int threads = 256;
    const int blocks = 2048;                 // grid-stride, ~8 iters/thread

    upsample_pca3d_kernel<<<blocks, threads, 0, stream>>>(x, mean, pca, out, n4);
}

// Round 3
// 115.759 us; speedup vs baseline: 1.3315x; 1.3315x over previous
//
#include <hip/hip_runtime.h>

// out[bc, 2d+k0, 2y+k1, 2z+k2] = x[bc,d,y,z] * p[k0*4+k1*2+k2] + m[...]
// x: (64,64,64,64) fp32, out: (64,128,128,128) fp32.
//
// Output-centric: thread-unit i owns out float4 [4i,4i+4) -> every wave store
// instruction is 64x16B fully dense (vs 32B-strided in R0, which half-filled
// every cache line and doubled per-line TA work).
// i bits: bc(6) | D(7) | Y(7) | Z4(5);  k0 = D&1, k1 = Y&1 (= tid bit 5).
// x float2 index: bc(6) | d(6) | y(6) | Z4(5).

typedef float f32x4 __attribute__((ext_vector_type(4)));
typedef float f32x2 __attribute__((ext_vector_type(2)));

__global__ __launch_bounds__(256) void upsample_pca3d_kernel(
    const float* __restrict__ x,
    const float* __restrict__ mean,
    const float* __restrict__ pca,
    float* __restrict__ out,
    int n4)                            // out_size/4 = 33554432
{
    // Coefficients (8 each) -> registers once.
    float p[8], m[8];
#pragma unroll
    for (int k = 0; k < 8; ++k) { p[k] = pca[k]; m[k] = mean[k]; }

    const int tid = threadIdx.x;
    const int k1  = (tid >> 5) & 1;    // Y parity: block bases are multiples of 256

    // Hoist the k1-level select (fixed per thread). Remaining per-iter select is k0 only.
    const float pA0 = k1 ? p[2] : p[0];   // k0 = 0
    const float pB0 = k1 ? p[3] : p[1];
    const float mA0 = k1 ? m[2] : m[0];
    const float mB0 = k1 ? m[3] : m[1];
    const float pA1 = k1 ? p[6] : p[4];   // k0 = 1
    const float pB1 = k1 ? p[7] : p[5];
    const float mA1 = k1 ? m[6] : m[4];
    const float mB1 = k1 ? m[7] : m[5];

    const f32x2* __restrict__ x2 = reinterpret_cast<const f32x2*>(x);
    f32x4* __restrict__ out4 = reinterpret_cast<f32x4*>(out);

    const int stride = gridDim.x * blockDim.x;
    for (int i = blockIdx.x * blockDim.x + tid; i < n4; i += stride) {
        const int Z4 = i & 31;
        const int y  = (i >> 6) & 63;
        const int k0 = (i >> 12) & 1;
        const int d  = (i >> 13) & 63;
        const int bc = i >> 19;

        const int xi = (bc << 17) + (d << 11) + (y << 5) + Z4;
        const f32x2 v = x2[xi];

        const float pA = k0 ? pA1 : pA0;
        const float pB = k0 ? pB1 : pB0;
        const float mA = k0 ? mA1 : mA0;
        const float mB = k0 ? mB1 : mB0;

        f32x4 o;
        o.x = fmaf(v.x, pA, mA);
        o.y = fmaf(v.x, pB, mB);
        o.z = fmaf(v.y, pA, mA);
        o.w = fmaf(v.y, pB, mB);
        __builtin_nontemporal_store(o, out4 + i);
    }
}

extern "C" void kernel_launch(void* const* d_in, const int* in_sizes, int n_in,
                              void* d_out, int out_size, void* d_ws, size_t ws_size,
                              hipStream_t stream) {
    const float* x    = (const float*)d_in[0];
    const float* mean = (const float*)d_in[1];
    const float* pca  = (const float*)d_in[2];
    float* out = (float*)d_out;

    const int n4 = out_size / 4;       // 33554432 float4 units
    const int threads = 256;
    const int blocks = 8192;           // grid-stride, 16 iters/thread

    upsample_pca3d_kernel<<<blocks, threads, 0, stream>>>(x, mean, pca, out, n4);
}

// Round 4
// 113.301 us; speedup vs baseline: 1.3604x; 1.0217x over previous
//
#include <hip/hip_runtime.h>

// out[bc, 2d+k0, 2Y'+k1, 2z+k2] = x[bc,d,Y'>>... ] — per-voxel rank-1 expand + 3D pixel shuffle.
// x: (64,64,64,64) fp32, out: (64,128,128,128) fp32.
//
// Thread-unit j owns BOTH k0 planes of one 8-float z-run half:
//   reads x float2 (bc,d,y,2*Z4..2*Z4+1) ONCE (nontemporal),
//   writes out4[o]        (k0=0)  and  out4[o+4096]  (k0=1),
// both stores fully dense per wave (64 x 16B contiguous).
// j bits: bc(6) | d(6) | Y(7) | Z4(5), Y = 2y+k1.
//   xi  = (bc<<17) + (d<<11) + ((Y>>1)<<5) + Z4          (float2 units)
//   o   = (bc<<19) + (d<<13) + (Y<<5) + Z4               (float4 units)

typedef float f32x4 __attribute__((ext_vector_type(4)));
typedef float f32x2 __attribute__((ext_vector_type(2)));

__global__ __launch_bounds__(256) void upsample_pca3d_kernel(
    const float* __restrict__ x,
    const float* __restrict__ mean,
    const float* __restrict__ pca,
    float* __restrict__ out,
    int nj)                            // out_size/8 = 16777216
{
    float p[8], m[8];
#pragma unroll
    for (int k = 0; k < 8; ++k) { p[k] = pca[k]; m[k] = mean[k]; }

    const int tid = threadIdx.x;
    const int k1  = (tid >> 5) & 1;    // j bit 5 = Y bit 0; invariant across grid-stride

    // k0 = 0 coefficients (indices k1*2, k1*2+1)
    const float pA0 = k1 ? p[2] : p[0];
    const float pB0 = k1 ? p[3] : p[1];
    const float mA0 = k1 ? m[2] : m[0];
    const float mB0 = k1 ? m[3] : m[1];
    // k0 = 1 coefficients (indices 4+k1*2, 5+k1*2)
    const float pA1 = k1 ? p[6] : p[4];
    const float pB1 = k1 ? p[7] : p[5];
    const float mA1 = k1 ? m[6] : m[4];
    const float mB1 = k1 ? m[7] : m[5];

    const f32x2* __restrict__ x2 = reinterpret_cast<const f32x2*>(x);
    f32x4* __restrict__ out4 = reinterpret_cast<f32x4*>(out);

    const int stride = gridDim.x * blockDim.x;
#pragma unroll 2
    for (int j = blockIdx.x * blockDim.x + tid; j < nj; j += stride) {
        const int Z4 = j & 31;
        const int Y  = (j >> 5) & 127;
        const int d  = (j >> 12) & 63;
        const int bc = j >> 18;

        const int xi = (bc << 17) + (d << 11) + ((Y >> 1) << 5) + Z4;
        const f32x2 v = __builtin_nontemporal_load(x2 + xi);

        const int o = (bc << 19) + (d << 13) + (Y << 5) + Z4;

        f32x4 o0, o1;
        o0.x = fmaf(v.x, pA0, mA0);
        o0.y = fmaf(v.x, pB0, mB0);
        o0.z = fmaf(v.y, pA0, mA0);
        o0.w = fmaf(v.y, pB0, mB0);
        o1.x = fmaf(v.x, pA1, mA1);
        o1.y = fmaf(v.x, pB1, mB1);
        o1.z = fmaf(v.y, pA1, mA1);
        o1.w = fmaf(v.y, pB1, mB1);

        __builtin_nontemporal_store(o0, out4 + o);           // k0 = 0 plane
        __builtin_nontemporal_store(o1, out4 + o + 4096);    // k0 = 1 plane (+64 KB)
    }
}

extern "C" void kernel_launch(void* const* d_in, const int* in_sizes, int n_in,
                              void* d_out, int out_size, void* d_ws, size_t ws_size,
                              hipStream_t stream) {
    const float* x    = (const float*)d_in[0];
    const float* mean = (const float*)d_in[1];
    const float* pca  = (const float*)d_in[2];
    float* out = (float*)d_out;

    const int nj = out_size / 8;       // 16777216 dual-float4 units
    const int threads = 256;
    const int blocks = 8192;           // grid-stride, 8 iters/thread

    upsample_pca3d_kernel<<<blocks, threads, 0, stream>>>(x, mean, pca, out, nj);
}